// Round 4
// baseline (472.231 us; speedup 1.0000x reference)
//
#include <hip/hip_runtime.h>

#define FNUM 40
#define DIM  64
#define NPAIR 780                 // 40*39/2
#define BLOCK 256
#define IN4   (FNUM * DIM / 4)    // 640 float4 per batch row
#define OUT4  (NPAIR * DIM / 4)   // 12480 float4 per batch row
#define XWF   (FNUM * DIM)        // 2560 floats per batch row
#define CHUNKS 4
#define PPC   (NPAIR / CHUNKS)    // 195 pairs per chunk
#define C4    (PPC * DIM / 4)     // 3120 float4 per chunk (= 12*256 + 48)
#define BATCH 2048

typedef float f32x4 __attribute__((ext_vector_type(4)));

// exact closed-form (i,j) for pair index p in combinations(range(40),2) order
// (verified bit-exact in round 3: discriminant <= 6241 is fp32-exact, fix-up
// guards the 1-ulp sqrt)
#define PAIR_IJ(p, i, j)                                               \
    int i = (int)((79.0f - sqrtf((float)(6241 - 8 * (p)))) * 0.5f);    \
    int _off = (i * (79 - i)) >> 1;                                    \
    if ((p) < _off) { --i; _off = (i * (79 - i)) >> 1; }               \
    else { int _o2 = ((i + 1) * (78 - i)) >> 1;                        \
           if ((p) >= _o2) { ++i; _off = _o2; } }                      \
    int j = i + 1 + ((p) - _off)

// ---------- kernel 1: xw[b][f][e] = sum_d in[b][f][d] * w[d][e] ----------
// Same readlane/wcol structure and d-ascending fmaf chain as the proven fused
// kernel (bit-identical result); reads in[] directly (no LDS), writes ws.
__global__ __launch_bounds__(BLOCK)
void gemm_xw(const float* __restrict__ in,
             const float* __restrict__ w,
             float* __restrict__ xw)
{
    const int tid  = threadIdx.x;
    const int b    = blockIdx.x;
    const int lane = tid & 63;
    const int wv   = tid >> 6;

    const float* __restrict__ inb = in + (size_t)b * XWF;
    float*       __restrict__ xwb = xw + (size_t)b * XWF;

    float wcol[DIM];
    #pragma unroll
    for (int d = 0; d < DIM; ++d) wcol[d] = w[d * DIM + lane];

    for (int r = 0; r < 10; ++r) {
        int f = wv * 10 + r;
        float rin = inb[f * DIM + lane];          // lane d holds in[f][d]
        float acc = 0.f;
        #pragma unroll
        for (int d = 0; d < DIM; ++d) {
            float bv = __uint_as_float(
                __builtin_amdgcn_readlane(__float_as_uint(rin), d));
            acc = fmaf(bv, wcol[d], acc);
        }
        xwb[f * DIM + lane] = acc;
    }
}

// ---------- kernel 2: pure store streamer ----------
// No LDS, no syncthreads, ~20 VGPR -> max occupancy. 8192 blocks; block
// (b, c) writes the contiguous 48.75 KB chunk out[b, c*195 .. c*195+194, :].
// a-reads hit L2 (xw dirty from kernel 1) / L1; v-reads hit L2 (in ~21 MB).
__global__ __launch_bounds__(BLOCK)
void pair_stream(const float* __restrict__ in,
                 const float* __restrict__ xw,
                 float* __restrict__ out)
{
    const int tid = threadIdx.x;
    const int b   = blockIdx.x >> 2;
    const int c   = blockIdx.x & 3;

    const f32x4* __restrict__ in4 = (const f32x4*)in + (size_t)b * IN4;
    const f32x4* __restrict__ xw4 = (const f32x4*)xw + (size_t)b * IN4;
    f32x4*       __restrict__ o4  = (f32x4*)out + (size_t)b * OUT4 + (size_t)c * C4;

    const int q     = tid & 15;        // invariant: stride BLOCK keeps q fixed
    const int pbase = c * PPC;
    const int prel0 = tid >> 4;

    #pragma unroll 4
    for (int k = 0; k < 12; ++k) {                 // 12 full strides
        int il = tid + k * BLOCK;
        int p  = pbase + prel0 + k * 16;
        PAIR_IJ(p, i, j);
        o4[il] = xw4[i * 16 + q] * in4[j * 16 + q];
    }
    if (tid < 48) {                                // tail: 3120 = 12*256 + 48
        int il = tid + 12 * BLOCK;
        int p  = pbase + prel0 + 12 * 16;
        PAIR_IJ(p, i, j);
        o4[il] = xw4[i * 16 + q] * in4[j * 16 + q];
    }
}

// ---------- fallback: proven fused kernel (420.97 us, round 2) ----------
__global__ __launch_bounds__(BLOCK)
void bilinear_fused(const float* __restrict__ in,
                    const float* __restrict__ w,
                    float* __restrict__ out)
{
    __shared__ float sIn[FNUM * DIM];
    __shared__ float sXW[FNUM * DIM];
    __shared__ unsigned char sPi[NPAIR];
    __shared__ unsigned char sPj[NPAIR];

    const int tid  = threadIdx.x;
    const int b    = blockIdx.x;
    const int lane = tid & 63;
    const int wv   = tid >> 6;

    const f32x4* in4 = (const f32x4*)in + (size_t)b * IN4;
    f32x4* sIn4 = (f32x4*)sIn;
    for (int k = tid; k < IN4; k += BLOCK) sIn4[k] = in4[k];

    if (tid < FNUM) {
        int i = tid;
        int off = i * (2 * FNUM - 1 - i) / 2;
        for (int j = i + 1; j < FNUM; ++j) {
            sPi[off] = (unsigned char)i;
            sPj[off] = (unsigned char)j;
            ++off;
        }
    }

    float wcol[DIM];
    #pragma unroll
    for (int d = 0; d < DIM; ++d) wcol[d] = w[d * DIM + lane];

    __syncthreads();

    for (int r = 0; r < 10; ++r) {
        int f = wv * 10 + r;
        float rin = sIn[f * DIM + lane];
        float acc = 0.f;
        #pragma unroll
        for (int d = 0; d < DIM; ++d) {
            float bv = __uint_as_float(
                __builtin_amdgcn_readlane(__float_as_uint(rin), d));
            acc = fmaf(bv, wcol[d], acc);
        }
        sXW[f * DIM + lane] = acc;
    }

    __syncthreads();

    const f32x4* sXW4 = (const f32x4*)sXW;
    f32x4* out4 = (f32x4*)out + (size_t)b * OUT4;
    for (int idx = tid; idx < OUT4; idx += BLOCK) {
        int p = idx >> 4;
        int qq = idx & 15;
        int i = sPi[p];
        int j = sPj[p];
        out4[idx] = sXW4[i * 16 + qq] * sIn4[j * 16 + qq];
    }
}

extern "C" void kernel_launch(void* const* d_in, const int* in_sizes, int n_in,
                              void* d_out, int out_size, void* d_ws, size_t ws_size,
                              hipStream_t stream)
{
    const float* in = (const float*)d_in[0];   // [2048, 40, 64] fp32
    const float* w  = (const float*)d_in[1];   // [64, 64] fp32
    float* out = (float*)d_out;                // [2048, 780*64] fp32

    const size_t need = (size_t)BATCH * XWF * sizeof(float);   // 20 MB
    if (d_ws != nullptr && ws_size >= need) {
        float* xw = (float*)d_ws;
        gemm_xw<<<BATCH, BLOCK, 0, stream>>>(in, w, xw);
        pair_stream<<<BATCH * CHUNKS, BLOCK, 0, stream>>>(in, xw, out);
    } else {
        bilinear_fused<<<BATCH, BLOCK, 0, stream>>>(in, w, out);
    }
}